// Round 9
// baseline (1419.250 us; speedup 1.0000x reference)
//
#include <hip/hip_runtime.h>
#include <math.h>

// ---------------------------------------------------------------------------
// SpatioTemporalOutageModel:
//   GCN(14->64) -> GCN(64->64)+county_bias -> LSTM(64->128, T=336) -> MLP(128->64->1)
//
// R9 (LSTM K-split across wave groups, 4 waves/SIMD):
//  - R6/R7/R8: three weight-residency schemes (L2-stream / AGPR / LDS) all
//    land 221-254us -> weight locality is NOT the limiter. The invariant:
//    2 waves/SIMD + 1 barrier/step; per-step exposed latency ~2.9us.
//  - Fix: 1024-thread blocks (16 waves = 4/SIMD), 16 nodes. Wave group 0
//    (waves 0-7) computes gate partials K 0..95 (x-part + h-frag0); group 1
//    K 96..191 (h-frags 1-3). 12 MFMAs / 12 weight frags (48 VGPRs) per wave
//    -> small enough to stay register-resident. Group-1 posts f32 partials
//    via LDS (b128, conflict-free); group-0 adds + elementwise + h-write.
//    2 barriers/step, but 2x latency hiding and half the serial work/wave.
//  - gbias staged in LDS (32KB): per-step re-reads never touch L2.
//  - (from R5/R6) k_tr2 folded into weights; rcp sigmoid/tanh; x prefetch.
// ---------------------------------------------------------------------------

#define T_DIM 336
#define N_DIM 3233
#define E_DIM 20000
#define FEAT  14
#define D_DIM 64
#define H_DIM 128
#define ET    (E_DIM + N_DIM)     // edges + self loops = 23233

// dynamic LDS layout for k_lstm
#define L_XH   0                          // f16 xh[2][16][136]   = 8704 B
#define L_EX   8704                       // f32 ex[8192]         = 32768 B (head reuses)
#define L_GB   (8704 + 32768)             // f32 gb[8192]         = 32768 B
#define L_HD   8704                       // f32 hd[16][132]      = 8448 (aliases ex)
#define L_ZS   (8704 + 8448)              // f32 zs[16][64]       = 4096 (aliases ex)
#define LDS_TOTAL (8704 + 32768 + 32768)  // 74240

typedef _Float16 f16;
typedef _Float16 half8_t __attribute__((ext_vector_type(8)));
typedef float float4_t __attribute__((ext_vector_type(4)));

__device__ __forceinline__ float sigf(float x) {
    return __builtin_amdgcn_rcpf(1.f + exp2f(-1.4426950408889634f * x));
}
__device__ __forceinline__ float tanhfast(float x) {
    return 1.f - 2.f * __builtin_amdgcn_rcpf(1.f + exp2f(2.8853900817779268f * x));
}

// ---------------- CSR build (deterministic) ----------------

__global__ void k_init(int* cnt, int* fill) {
    int i = blockIdx.x * 256 + threadIdx.x;
    if (i < N_DIM) { cnt[i] = 0; fill[i] = 0; }
}

__global__ void k_cnt(const int* __restrict__ ei, int* cnt) {
    int e = blockIdx.x * 256 + threadIdx.x;
    if (e < E_DIM) atomicAdd(&cnt[ei[E_DIM + e]], 1);
}

__global__ void k_scan(const int* __restrict__ cnt, int* __restrict__ rowp) {
    __shared__ int csum[1024];
    int tid = threadIdx.x;
    int base = tid * 4;
    int v[4];
    int s = 0;
    #pragma unroll
    for (int m = 0; m < 4; m++) {
        int idx = base + m;
        int len = (idx < N_DIM) ? (cnt[idx] + 1) : 0;
        v[m] = s; s += len;
    }
    csum[tid] = s;
    __syncthreads();
    for (int off = 1; off < 1024; off <<= 1) {
        int t2 = (tid >= off) ? csum[tid - off] : 0;
        __syncthreads();
        csum[tid] += t2;
        __syncthreads();
    }
    int pre = (tid > 0) ? csum[tid - 1] : 0;
    #pragma unroll
    for (int m = 0; m < 4; m++) {
        int idx = base + m;
        if (idx <= N_DIM) rowp[idx] = pre + v[m];
    }
}

__global__ void k_fill(const int* __restrict__ ei, const int* __restrict__ rowp,
                       int* fill, int* __restrict__ eid) {
    int e = blockIdx.x * 256 + threadIdx.x;
    if (e < ET) {
        int d = (e < E_DIM) ? ei[E_DIM + e] : (e - E_DIM);
        int p = rowp[d] + atomicAdd(&fill[d], 1);
        eid[p] = e;
    }
}

__global__ void k_sortdeg(const float* __restrict__ ew, const int* __restrict__ rowp,
                          int* __restrict__ eid, float* __restrict__ dis) {
    int n = blockIdx.x * 256 + threadIdx.x;
    if (n >= N_DIM) return;
    int p0 = rowp[n], p1 = rowp[n + 1];
    for (int i = p0 + 1; i < p1; i++) {
        int key = eid[i];
        int j = i - 1;
        while (j >= p0 && eid[j] > key) { eid[j + 1] = eid[j]; j--; }
        eid[j + 1] = key;
    }
    float deg = 0.f;
    for (int p = p0; p < p1; p++) {
        int e = eid[p];
        deg += (e < E_DIM) ? ew[e] : 1.0f;
    }
    dis[n] = rsqrtf(deg);
}

__global__ void k_csrmat(const int* __restrict__ ei, const float* __restrict__ ew,
                         const float* __restrict__ dis, const int* __restrict__ rowp,
                         const int* __restrict__ eid, int* __restrict__ csrc,
                         float* __restrict__ cnrm) {
    int n = blockIdx.x * 256 + threadIdx.x;
    if (n >= N_DIM) return;
    float dn = dis[n];
    int p0 = rowp[n], p1 = rowp[n + 1];
    for (int p = p0; p < p1; p++) {
        int e = eid[p];
        int s; float w;
        if (e < E_DIM) { s = ei[e]; w = ew[e]; }
        else           { s = e - E_DIM; w = 1.0f; }
        csrc[p] = s;
        cnrm[p] = dis[s] * w * dn;
    }
}

// ---------------- weight prep: fold W2 into Wih, pack B-fragments ----------------
// fragment idx = ((wv*4+ct)*6+ks)*64 + lane; gate g = 128ct+16wv+r.
// ks 0-1: W'[k][g] = sum_d W2[k][d]*Wih[g][d]   (k = 32ks+8q+j, ah-space)
// ks 2-5: Whh[g][k-64]                          (k-64 = 32(ks-2)+8q+j)
__global__ void k_wprep(const float* __restrict__ W2, const float* __restrict__ Wih,
                        const float* __restrict__ Whh, f16* __restrict__ wfbuf) {
    int idx = blockIdx.x * 256 + threadIdx.x;
    if (idx >= 8 * 4 * 6 * 64) return;
    int lane = idx & 63;
    int ks = (idx >> 6) % 6;
    int ct = ((idx >> 6) / 6) & 3;
    int wv = (idx >> 6) / 24;
    int q = lane >> 4, r = lane & 15;
    int g = 128 * ct + 16 * wv + r;
    f16* dst = wfbuf + (long)idx * 8;
    if (ks < 2) {
        const float* wir = Wih + (long)g * 64;
        #pragma unroll
        for (int j = 0; j < 8; j++) {
            int k = 32 * ks + 8 * q + j;
            const float* w2r = W2 + (long)k * 64;
            float s = 0.f;
            #pragma unroll 16
            for (int d = 0; d < 64; d++) s += w2r[d] * wir[d];
            dst[j] = (f16)s;
        }
    } else {
        const float* src = Whh + (long)g * 128 + 32 * (ks - 2) + 8 * q;
        #pragma unroll
        for (int j = 0; j < 8; j++) dst[j] = (f16)src[j];
    }
}

// gbias[n][g] = bih[g]+bhh[g] + sum_d (b2[d]+county[n][d])*Wih[g][d]
__global__ void k_gbias(const float* __restrict__ county, const float* __restrict__ b2,
                        const float* __restrict__ Wih, const float* __restrict__ bih,
                        const float* __restrict__ bhh, float* __restrict__ gbias) {
    long id = (long)blockIdx.x * 256 + threadIdx.x;
    if (id >= (long)N_DIM * 512) return;
    int n = (int)(id >> 9), g = (int)(id & 511);
    const float* wir = Wih + (long)g * 64;
    const float* cn = county + (long)n * 64;
    float s = bih[g] + bhh[g];
    #pragma unroll 16
    for (int d = 0; d < 64; d++) s += (b2[d] + cn[d]) * wir[d];
    gbias[id] = s;
}

// ---------------- GCN1a: aggX = A.x  (14-dim gather, 4 timesteps/wave) ----------------
__global__ void k_aggx(const float* __restrict__ x, const int* __restrict__ rowp,
                       const int* __restrict__ csrc, const float* __restrict__ cnrm,
                       float* __restrict__ aggX, int tc) {
    int lane = threadIdx.x & 63;
    long wid = ((long)blockIdx.x * 256 + threadIdx.x) >> 6;
    int ntg = (tc + 3) >> 2;
    if (wid >= (long)N_DIM * ntg) return;
    int n = (int)(wid % N_DIM);
    int tg = (int)(wid / N_DIM);
    int j = lane >> 4, d = lane & 15;
    int tj = 4 * tg + j;
    bool live = (d < FEAT) && (tj < tc);
    float acc = 0.f;
    int p0 = rowp[n], p1 = rowp[n + 1];
    for (int p = p0; p < p1; p++) {
        int s = csrc[p];
        float w = cnrm[p];
        if (live) acc += w * x[((long)tj * N_DIM + s) * FEAT + d];
    }
    if (tj < tc) aggX[((long)tj * N_DIM + n) * 16 + d] = acc;
}

// ---------------- GCN1b: h = relu(aggX.W1 + b1) -> f16 ----------------
__global__ void k_tr1(const float* __restrict__ aggX, const float* __restrict__ W1,
                      const float* __restrict__ b1, f16* __restrict__ h, long rows) {
    int lane = threadIdx.x & 63;
    long wid = ((long)blockIdx.x * 256 + threadIdx.x) >> 6;
    float wc[FEAT];
    #pragma unroll
    for (int k = 0; k < FEAT; k++) wc[k] = W1[k * 64 + lane];
    float bb = b1[lane];
    long r0 = wid * 2;
    if (r0 >= rows) return;
    long r1 = r0 + 1;
    bool has1 = (r1 < rows);
    const float* p0 = aggX + r0 * 16;
    const float* p1 = aggX + (has1 ? r1 : r0) * 16;
    float a0 = bb, a1 = bb;
    #pragma unroll
    for (int k = 0; k < FEAT; k++) { a0 += p0[k] * wc[k]; a1 += p1[k] * wc[k]; }
    h[r0 * 64 + lane] = (f16)fmaxf(a0, 0.f);
    if (has1) h[r1 * 64 + lane] = (f16)fmaxf(a1, 0.f);
}

// ---------------- GCN2a: ah = A.h  (f16 gather -> f16 out, 4 timesteps/wave) ----------------
__global__ void k_agg2(const f16* __restrict__ h, const int* __restrict__ rowp,
                       const int* __restrict__ csrc, const float* __restrict__ cnrm,
                       f16* __restrict__ ah, int tc) {
    int lane = threadIdx.x & 63;
    long wid = ((long)blockIdx.x * 256 + threadIdx.x) >> 6;
    int ntg = (tc + 3) >> 2;
    if (wid >= (long)N_DIM * ntg) return;
    int n = (int)(wid % N_DIM);
    int tg = (int)(wid / N_DIM);
    int tbase = 4 * tg;
    float acc0 = 0.f, acc1 = 0.f, acc2 = 0.f, acc3 = 0.f;
    int p0 = rowp[n], p1 = rowp[n + 1];
    for (int p = p0; p < p1; p++) {
        int s = csrc[p];
        float w = cnrm[p];
        const f16* base = h + ((long)tbase * N_DIM + s) * 64 + lane;
        acc0 += w * (float)base[0];
        if (tbase + 1 < tc) acc1 += w * (float)base[(long)N_DIM * 64];
        if (tbase + 2 < tc) acc2 += w * (float)base[(long)N_DIM * 128];
        if (tbase + 3 < tc) acc3 += w * (float)base[(long)N_DIM * 192];
    }
    f16* dst = ah + ((long)tbase * N_DIM + n) * 64 + lane;
    dst[0] = (f16)acc0;
    if (tbase + 1 < tc) dst[(long)N_DIM * 64] = (f16)acc1;
    if (tbase + 2 < tc) dst[(long)N_DIM * 128] = (f16)acc2;
    if (tbase + 3 < tc) dst[(long)N_DIM * 192] = (f16)acc3;
}

// ---------------- LSTM chunk: K-split dual wave-groups, 1024 threads ----------------
// Group 0 (waves 0-7):  gates partial K 0..95  (x via regs + h-frag0), owns state,
//                       elementwise, h-write. Thread (wv,q,r): nodes 4q+reg,
//                       unit u=16wv+r, gate-types ct in acc[ct][reg].
// Group 1 (waves 8-15): gates partial K 96..191 (h-frags 1-3), posts f32
//                       partials to LDS.
__global__ __launch_bounds__(1024, 1) void k_lstm(
    const f16* __restrict__ ah, const f16* __restrict__ wfbuf,
    const float* __restrict__ gbias,
    const float* __restrict__ Wm1, const float* __restrict__ bm1,
    const float* __restrict__ Wm2, const float* __restrict__ bm2,
    float* __restrict__ Hst, float* __restrict__ Cst,
    int tc, int do_init, int do_head, float* __restrict__ out) {
    extern __shared__ __align__(16) char smem[];
    f16 (*xh)[16][136] = (f16(*)[16][136])(smem + L_XH);
    float* ex = (float*)(smem + L_EX);
    float* gb = (float*)(smem + L_GB);
    float (*hd)[132] = (float(*)[132])(smem + L_HD);
    float (*zs)[64]  = (float(*)[64])(smem + L_ZS);

    int tid = threadIdx.x;
    int grp = tid >> 9;               // 0 or 1 (wave-uniform)
    int wv = (tid >> 6) & 7;          // wave within group
    int lane = tid & 63, q = lane >> 4, r = lane & 15;
    int nb = blockIdx.x * 16;
    int cnt = min(16, N_DIM - nb);
    int u = 16 * wv + r;

    // ---- weight fragments: group 0 -> ks {0,1,2}; group 1 -> ks {3,4,5} ----
    half8_t wf[4][3];
    #pragma unroll
    for (int ct = 0; ct < 4; ct++)
        #pragma unroll
        for (int j = 0; j < 3; j++) {
            int ks = grp * 3 + j;
            wf[ct][j] = *(const half8_t*)&wfbuf[(long)((((wv * 4 + ct) * 6 + ks) << 6) + lane) * 8];
        }

    // ---- group 0: stage per-node gate bias into LDS; load state; write h ----
    float cv[4], hvv[4];
    half8_t xa, xb;
    int xrow = nb + r; if (xrow >= N_DIM) xrow = N_DIM - 1;
    if (!grp) {
        #pragma unroll
        for (int ct = 0; ct < 4; ct++) {
            #pragma unroll
            for (int reg = 0; reg < 4; reg++) {
                int gn = nb + 4 * q + reg; if (gn >= N_DIM) gn = N_DIM - 1;
                gb[(((wv * 4 + ct) << 6) + lane) * 4 + reg] =
                    gbias[(long)gn * 512 + 128 * ct + u];
            }
        }
        #pragma unroll
        for (int reg = 0; reg < 4; reg++) {
            int node = 4 * q + reg;
            bool live = (!do_init) && (node < cnt);
            hvv[reg] = live ? Hst[(long)(nb + node) * H_DIM + u] : 0.f;
            cv[reg]  = live ? Cst[(long)(nb + node) * H_DIM + u] : 0.f;
            xh[0][node][u] = (f16)hvv[reg];
        }
        xa = *(const half8_t*)(ah + (long)xrow * 64 + 8 * q);
        xb = *(const half8_t*)(ah + (long)xrow * 64 + 32 + 8 * q);
    }

    int buf = 0;
    __syncthreads();   // h[0], gb staged

    for (int t = 0; t < tc; t++) {
        float4_t acc[4];
        if (!grp) {
            // K 0..95: x (regs) + h units 0..31 (LDS)
            half8_t a2 = *(const half8_t*)&xh[buf][r][8 * q];
            #pragma unroll
            for (int ct = 0; ct < 4; ct++)
                acc[ct] = *(const float4_t*)&gb[(((wv * 4 + ct) << 6) + lane) * 4];
            #pragma unroll
            for (int ct = 0; ct < 4; ct++)
                acc[ct] = __builtin_amdgcn_mfma_f32_16x16x32_f16(xa, wf[ct][0], acc[ct], 0, 0, 0);
            #pragma unroll
            for (int ct = 0; ct < 4; ct++)
                acc[ct] = __builtin_amdgcn_mfma_f32_16x16x32_f16(xb, wf[ct][1], acc[ct], 0, 0, 0);
            // prefetch next x while MFMAs drain
            int tn = (t + 1 < tc) ? t + 1 : t;
            const f16* xp = ah + ((long)tn * N_DIM + xrow) * 64;
            xa = *(const half8_t*)(xp + 8 * q);
            xb = *(const half8_t*)(xp + 32 + 8 * q);
            #pragma unroll
            for (int ct = 0; ct < 4; ct++)
                acc[ct] = __builtin_amdgcn_mfma_f32_16x16x32_f16(a2, wf[ct][2], acc[ct], 0, 0, 0);
        } else {
            // K 96..191: h units 32..127 (LDS)
            half8_t a3 = *(const half8_t*)&xh[buf][r][32 + 8 * q];
            half8_t a4 = *(const half8_t*)&xh[buf][r][64 + 8 * q];
            half8_t a5 = *(const half8_t*)&xh[buf][r][96 + 8 * q];
            #pragma unroll
            for (int ct = 0; ct < 4; ct++) acc[ct] = (float4_t){0.f, 0.f, 0.f, 0.f};
            #pragma unroll
            for (int ct = 0; ct < 4; ct++)
                acc[ct] = __builtin_amdgcn_mfma_f32_16x16x32_f16(a3, wf[ct][0], acc[ct], 0, 0, 0);
            #pragma unroll
            for (int ct = 0; ct < 4; ct++)
                acc[ct] = __builtin_amdgcn_mfma_f32_16x16x32_f16(a4, wf[ct][1], acc[ct], 0, 0, 0);
            #pragma unroll
            for (int ct = 0; ct < 4; ct++)
                acc[ct] = __builtin_amdgcn_mfma_f32_16x16x32_f16(a5, wf[ct][2], acc[ct], 0, 0, 0);
            #pragma unroll
            for (int ct = 0; ct < 4; ct++)
                *(float4_t*)&ex[(((wv * 4 + ct) << 6) + lane) * 4] = acc[ct];
        }
        __syncthreads();   // partials posted

        if (!grp) {
            #pragma unroll
            for (int ct = 0; ct < 4; ct++) {
                float4_t e = *(const float4_t*)&ex[(((wv * 4 + ct) << 6) + lane) * 4];
                acc[ct] += e;
            }
            #pragma unroll
            for (int reg = 0; reg < 4; reg++) {
                float gi = acc[0][reg], gf = acc[1][reg], gg = acc[2][reg], go = acc[3][reg];
                float c = sigf(gf) * cv[reg] + sigf(gi) * tanhfast(gg);
                float hh = sigf(go) * tanhfast(c);
                cv[reg] = c; hvv[reg] = hh;
                xh[buf ^ 1][4 * q + reg][u] = (f16)hh;
            }
        }
        __syncthreads();   // h(t) visible to both groups
        buf ^= 1;
    }

    if (!grp) {
        #pragma unroll
        for (int reg = 0; reg < 4; reg++) {
            int node = 4 * q + reg;
            if (node < cnt) {
                Hst[(long)(nb + node) * H_DIM + u] = hvv[reg];
                Cst[(long)(nb + node) * H_DIM + u] = cv[reg];
            }
        }
    }
    if (!do_head) return;

    if (!grp) {
        #pragma unroll
        for (int reg = 0; reg < 4; reg++) hd[4 * q + reg][u] = hvv[reg];
    }
    __syncthreads();

    // z = relu(h @ Wm1 + bm1): 1024 threads, one (node,m) each
    {
        int n = tid >> 6, m = tid & 63;
        float a = bm1[m];
        #pragma unroll 8
        for (int k = 0; k < H_DIM; k++) a += hd[n][k] * Wm1[k * 64 + m];
        zs[n][m] = fmaxf(a, 0.f);
    }
    __syncthreads();
    if (tid < cnt) {
        float a = bm2[0];
        #pragma unroll 8
        for (int m = 0; m < 64; m++) a += zs[tid][m] * Wm2[m];
        out[nb + tid] = a;
    }
}

// ---------------------------------------------------------------------------

extern "C" void kernel_launch(void* const* d_in, const int* in_sizes, int n_in,
                              void* d_out, int out_size, void* d_ws, size_t ws_size,
                              hipStream_t stream) {
    const float* x   = (const float*)d_in[0];
    const int*   ei  = (const int*)d_in[1];
    const float* ew  = (const float*)d_in[2];
    const float* W1  = (const float*)d_in[3];
    const float* b1  = (const float*)d_in[4];
    const float* W2  = (const float*)d_in[5];
    const float* b2  = (const float*)d_in[6];
    const float* cb  = (const float*)d_in[7];
    const float* Wih = (const float*)d_in[8];
    const float* Whh = (const float*)d_in[9];
    const float* bih = (const float*)d_in[10];
    const float* bhh = (const float*)d_in[11];
    const float* Wm1 = (const float*)d_in[12];
    const float* bm1 = (const float*)d_in[13];
    const float* Wm2 = (const float*)d_in[14];
    const float* bm2 = (const float*)d_in[15];
    float* out = (float*)d_out;
    (void)in_sizes; (void)n_in; (void)out_size;

    // allow >64KB dynamic LDS for k_lstm (host-side, capture-safe)
    hipFuncSetAttribute((const void*)k_lstm,
                        hipFuncAttributeMaxDynamicSharedMemorySize, LDS_TOTAL);

    char* ws = (char*)d_ws;
    size_t off = 0;
    auto alloc = [&](size_t bytes) -> char* {
        char* p = ws + off;
        off = (off + bytes + 255) & ~(size_t)255;
        return p;
    };
    float* dis   = (float*)alloc(N_DIM * 4);
    int*   cnt   = (int*)alloc(N_DIM * 4);
    int*   fill  = (int*)alloc(N_DIM * 4);
    int*   rowp  = (int*)alloc((N_DIM + 1) * 4);
    int*   eid   = (int*)alloc(ET * 4);
    int*   csrc  = (int*)alloc(ET * 4);
    float* cnrm  = (float*)alloc(ET * 4);
    float* Hst   = (float*)alloc((size_t)N_DIM * H_DIM * 4);
    float* Cst   = (float*)alloc((size_t)N_DIM * H_DIM * 4);
    f16*   wfbuf = (f16*)alloc((size_t)8 * 4 * 6 * 64 * 8 * 2);
    float* gbias = (float*)alloc((size_t)N_DIM * 512 * 4);

    // largest Tc dividing 336 whose chunk buffers (rows*320B) fit
    const int cand[] = {336, 168, 112, 84, 56, 48, 28, 16, 8, 4};
    int Tc = 4;
    for (int i = 0; i < 10; i++) {
        size_t need = off + (size_t)cand[i] * N_DIM * 320 + 4096;
        if (need <= ws_size) { Tc = cand[i]; break; }
    }
    long rows = (long)Tc * N_DIM;
    float* aggX  = (float*)alloc(rows * 64);    // [rows][16] fp32 (14 used)
    f16*   hbuf  = (f16*)alloc(rows * 128);     // h f16
    f16*   ahbuf = (f16*)alloc(rows * 128);     // ah f16

    // --- one-time: CSR build + weight fold/pack + per-node gate bias ---
    k_init<<<(N_DIM + 255) / 256, 256, 0, stream>>>(cnt, fill);
    k_cnt<<<(E_DIM + 255) / 256, 256, 0, stream>>>(ei, cnt);
    k_scan<<<1, 1024, 0, stream>>>(cnt, rowp);
    k_fill<<<(ET + 255) / 256, 256, 0, stream>>>(ei, rowp, fill, eid);
    k_sortdeg<<<(N_DIM + 255) / 256, 256, 0, stream>>>(ew, rowp, eid, dis);
    k_csrmat<<<(N_DIM + 255) / 256, 256, 0, stream>>>(ei, ew, dis, rowp, eid, csrc, cnrm);
    k_wprep<<<48, 256, 0, stream>>>(W2, Wih, Whh, wfbuf);
    k_gbias<<<(int)(((long)N_DIM * 512 + 255) / 256), 256, 0, stream>>>(cb, b2, Wih, bih, bhh, gbias);

    int ntg = (Tc + 3) >> 2;
    long aggWaves = (long)N_DIM * ntg;
    int aggBlocks = (int)((aggWaves + 3) / 4);
    int trBlocks  = (int)(((rows + 1) / 2 + 3) / 4);
    int lblocks   = (N_DIM + 15) / 16;
    int nChunks   = T_DIM / Tc;

    for (int c = 0; c < nChunks; c++) {
        long t0 = (long)c * Tc;
        k_aggx<<<aggBlocks, 256, 0, stream>>>(x + t0 * N_DIM * FEAT, rowp, csrc, cnrm, aggX, Tc);
        k_tr1<<<trBlocks, 256, 0, stream>>>(aggX, W1, b1, hbuf, rows);
        k_agg2<<<aggBlocks, 256, 0, stream>>>(hbuf, rowp, csrc, cnrm, ahbuf, Tc);
        k_lstm<<<lblocks, 1024, LDS_TOTAL, stream>>>(ahbuf, wfbuf, gbias, Wm1, bm1, Wm2, bm2,
                                                     Hst, Cst, Tc, c == 0 ? 1 : 0,
                                                     c == nChunks - 1 ? 1 : 0, out);
    }
}

// Round 10
// 1328.314 us; speedup vs baseline: 1.0685x; 1.0685x over previous
//
#include <hip/hip_runtime.h>
#include <math.h>

// ---------------------------------------------------------------------------
// SpatioTemporalOutageModel:
//   GCN(14->64) -> GCN(64->64)+county_bias -> LSTM(64->128, T=336) -> MLP(128->64->1)
//
// R10 (LSTM: no arrays in the hot path -> force register promotion):
//  - R3-R9 invariant: ~2us/step regardless of weight residency scheme, and
//    VGPR_Count always FAR below the declared register arrays (92 vs 96+,
//    68, 60...). Diagnosis (guide rule #20): arrays of ext_vector types
//    lower to allocas -> scratch; every step reloads ~1.5-4KB/thread from
//    scratch. All prior "residency" fixes still declared ARRAYS.
//  - Fix: R6 structure (512thr, 8 waves, 16 nodes, 1 barrier/step) rewritten
//    with 24 NAMED weight fragments + named acc/bias/state (macro-generated
//    straight-line code, zero indexable aggregates). Canonical promotion.
//  - (from R5/R6) k_tr2 folded into weights (W'=W2@Wih^T + per-node gbias);
//    rcp sigmoid/tanh; mid-loop x prefetch.
// ---------------------------------------------------------------------------

#define T_DIM 336
#define N_DIM 3233
#define E_DIM 20000
#define FEAT  14
#define D_DIM 64
#define H_DIM 128
#define ET    (E_DIM + N_DIM)     // edges + self loops = 23233

typedef _Float16 f16;
typedef _Float16 half8_t __attribute__((ext_vector_type(8)));
typedef float float4_t __attribute__((ext_vector_type(4)));

__device__ __forceinline__ float sigf(float x) {
    return __builtin_amdgcn_rcpf(1.f + exp2f(-1.4426950408889634f * x));
}
__device__ __forceinline__ float tanhfast(float x) {
    return 1.f - 2.f * __builtin_amdgcn_rcpf(1.f + exp2f(2.8853900817779268f * x));
}

// ---------------- CSR build (deterministic) ----------------

__global__ void k_init(int* cnt, int* fill) {
    int i = blockIdx.x * 256 + threadIdx.x;
    if (i < N_DIM) { cnt[i] = 0; fill[i] = 0; }
}

__global__ void k_cnt(const int* __restrict__ ei, int* cnt) {
    int e = blockIdx.x * 256 + threadIdx.x;
    if (e < E_DIM) atomicAdd(&cnt[ei[E_DIM + e]], 1);
}

__global__ void k_scan(const int* __restrict__ cnt, int* __restrict__ rowp) {
    __shared__ int csum[1024];
    int tid = threadIdx.x;
    int base = tid * 4;
    int v[4];
    int s = 0;
    #pragma unroll
    for (int m = 0; m < 4; m++) {
        int idx = base + m;
        int len = (idx < N_DIM) ? (cnt[idx] + 1) : 0;
        v[m] = s; s += len;
    }
    csum[tid] = s;
    __syncthreads();
    for (int off = 1; off < 1024; off <<= 1) {
        int t2 = (tid >= off) ? csum[tid - off] : 0;
        __syncthreads();
        csum[tid] += t2;
        __syncthreads();
    }
    int pre = (tid > 0) ? csum[tid - 1] : 0;
    #pragma unroll
    for (int m = 0; m < 4; m++) {
        int idx = base + m;
        if (idx <= N_DIM) rowp[idx] = pre + v[m];
    }
}

__global__ void k_fill(const int* __restrict__ ei, const int* __restrict__ rowp,
                       int* fill, int* __restrict__ eid) {
    int e = blockIdx.x * 256 + threadIdx.x;
    if (e < ET) {
        int d = (e < E_DIM) ? ei[E_DIM + e] : (e - E_DIM);
        int p = rowp[d] + atomicAdd(&fill[d], 1);
        eid[p] = e;
    }
}

__global__ void k_sortdeg(const float* __restrict__ ew, const int* __restrict__ rowp,
                          int* __restrict__ eid, float* __restrict__ dis) {
    int n = blockIdx.x * 256 + threadIdx.x;
    if (n >= N_DIM) return;
    int p0 = rowp[n], p1 = rowp[n + 1];
    for (int i = p0 + 1; i < p1; i++) {
        int key = eid[i];
        int j = i - 1;
        while (j >= p0 && eid[j] > key) { eid[j + 1] = eid[j]; j--; }
        eid[j + 1] = key;
    }
    float deg = 0.f;
    for (int p = p0; p < p1; p++) {
        int e = eid[p];
        deg += (e < E_DIM) ? ew[e] : 1.0f;
    }
    dis[n] = rsqrtf(deg);
}

__global__ void k_csrmat(const int* __restrict__ ei, const float* __restrict__ ew,
                         const float* __restrict__ dis, const int* __restrict__ rowp,
                         const int* __restrict__ eid, int* __restrict__ csrc,
                         float* __restrict__ cnrm) {
    int n = blockIdx.x * 256 + threadIdx.x;
    if (n >= N_DIM) return;
    float dn = dis[n];
    int p0 = rowp[n], p1 = rowp[n + 1];
    for (int p = p0; p < p1; p++) {
        int e = eid[p];
        int s; float w;
        if (e < E_DIM) { s = ei[e]; w = ew[e]; }
        else           { s = e - E_DIM; w = 1.0f; }
        csrc[p] = s;
        cnrm[p] = dis[s] * w * dn;
    }
}

// ---------------- weight prep: fold W2 into Wih, pack B-fragments ----------------
// fragment idx = ((wv*4+ct)*6+ks)*64 + lane; gate g = 128ct+16wv+r.
// ks 0-1: W'[k][g] = sum_d W2[k][d]*Wih[g][d]   (k = 32ks+8q+j, ah-space)
// ks 2-5: Whh[g][k-64]                          (k-64 = 32(ks-2)+8q+j)
__global__ void k_wprep(const float* __restrict__ W2, const float* __restrict__ Wih,
                        const float* __restrict__ Whh, f16* __restrict__ wfbuf) {
    int idx = blockIdx.x * 256 + threadIdx.x;
    if (idx >= 8 * 4 * 6 * 64) return;
    int lane = idx & 63;
    int ks = (idx >> 6) % 6;
    int ct = ((idx >> 6) / 6) & 3;
    int wv = (idx >> 6) / 24;
    int q = lane >> 4, r = lane & 15;
    int g = 128 * ct + 16 * wv + r;
    f16* dst = wfbuf + (long)idx * 8;
    if (ks < 2) {
        const float* wir = Wih + (long)g * 64;
        #pragma unroll
        for (int j = 0; j < 8; j++) {
            int k = 32 * ks + 8 * q + j;
            const float* w2r = W2 + (long)k * 64;
            float s = 0.f;
            #pragma unroll 16
            for (int d = 0; d < 64; d++) s += w2r[d] * wir[d];
            dst[j] = (f16)s;
        }
    } else {
        const float* src = Whh + (long)g * 128 + 32 * (ks - 2) + 8 * q;
        #pragma unroll
        for (int j = 0; j < 8; j++) dst[j] = (f16)src[j];
    }
}

// gbias[n][g] = bih[g]+bhh[g] + sum_d (b2[d]+county[n][d])*Wih[g][d]
__global__ void k_gbias(const float* __restrict__ county, const float* __restrict__ b2,
                        const float* __restrict__ Wih, const float* __restrict__ bih,
                        const float* __restrict__ bhh, float* __restrict__ gbias) {
    long id = (long)blockIdx.x * 256 + threadIdx.x;
    if (id >= (long)N_DIM * 512) return;
    int n = (int)(id >> 9), g = (int)(id & 511);
    const float* wir = Wih + (long)g * 64;
    const float* cn = county + (long)n * 64;
    float s = bih[g] + bhh[g];
    #pragma unroll 16
    for (int d = 0; d < 64; d++) s += (b2[d] + cn[d]) * wir[d];
    gbias[id] = s;
}

// ---------------- GCN1a: aggX = A.x  (14-dim gather, 4 timesteps/wave) ----------------
__global__ void k_aggx(const float* __restrict__ x, const int* __restrict__ rowp,
                       const int* __restrict__ csrc, const float* __restrict__ cnrm,
                       float* __restrict__ aggX, int tc) {
    int lane = threadIdx.x & 63;
    long wid = ((long)blockIdx.x * 256 + threadIdx.x) >> 6;
    int ntg = (tc + 3) >> 2;
    if (wid >= (long)N_DIM * ntg) return;
    int n = (int)(wid % N_DIM);
    int tg = (int)(wid / N_DIM);
    int j = lane >> 4, d = lane & 15;
    int tj = 4 * tg + j;
    bool live = (d < FEAT) && (tj < tc);
    float acc = 0.f;
    int p0 = rowp[n], p1 = rowp[n + 1];
    for (int p = p0; p < p1; p++) {
        int s = csrc[p];
        float w = cnrm[p];
        if (live) acc += w * x[((long)tj * N_DIM + s) * FEAT + d];
    }
    if (tj < tc) aggX[((long)tj * N_DIM + n) * 16 + d] = acc;
}

// ---------------- GCN1b: h = relu(aggX.W1 + b1) -> f16 ----------------
__global__ void k_tr1(const float* __restrict__ aggX, const float* __restrict__ W1,
                      const float* __restrict__ b1, f16* __restrict__ h, long rows) {
    int lane = threadIdx.x & 63;
    long wid = ((long)blockIdx.x * 256 + threadIdx.x) >> 6;
    float wc[FEAT];
    #pragma unroll
    for (int k = 0; k < FEAT; k++) wc[k] = W1[k * 64 + lane];
    float bb = b1[lane];
    long r0 = wid * 2;
    if (r0 >= rows) return;
    long r1 = r0 + 1;
    bool has1 = (r1 < rows);
    const float* p0 = aggX + r0 * 16;
    const float* p1 = aggX + (has1 ? r1 : r0) * 16;
    float a0 = bb, a1 = bb;
    #pragma unroll
    for (int k = 0; k < FEAT; k++) { a0 += p0[k] * wc[k]; a1 += p1[k] * wc[k]; }
    h[r0 * 64 + lane] = (f16)fmaxf(a0, 0.f);
    if (has1) h[r1 * 64 + lane] = (f16)fmaxf(a1, 0.f);
}

// ---------------- GCN2a: ah = A.h  (f16 gather -> f16 out, 4 timesteps/wave) ----------------
__global__ void k_agg2(const f16* __restrict__ h, const int* __restrict__ rowp,
                       const int* __restrict__ csrc, const float* __restrict__ cnrm,
                       f16* __restrict__ ah, int tc) {
    int lane = threadIdx.x & 63;
    long wid = ((long)blockIdx.x * 256 + threadIdx.x) >> 6;
    int ntg = (tc + 3) >> 2;
    if (wid >= (long)N_DIM * ntg) return;
    int n = (int)(wid % N_DIM);
    int tg = (int)(wid / N_DIM);
    int tbase = 4 * tg;
    float acc0 = 0.f, acc1 = 0.f, acc2 = 0.f, acc3 = 0.f;
    int p0 = rowp[n], p1 = rowp[n + 1];
    for (int p = p0; p < p1; p++) {
        int s = csrc[p];
        float w = cnrm[p];
        const f16* base = h + ((long)tbase * N_DIM + s) * 64 + lane;
        acc0 += w * (float)base[0];
        if (tbase + 1 < tc) acc1 += w * (float)base[(long)N_DIM * 64];
        if (tbase + 2 < tc) acc2 += w * (float)base[(long)N_DIM * 128];
        if (tbase + 3 < tc) acc3 += w * (float)base[(long)N_DIM * 192];
    }
    f16* dst = ah + ((long)tbase * N_DIM + n) * 64 + lane;
    dst[0] = (f16)acc0;
    if (tbase + 1 < tc) dst[(long)N_DIM * 64] = (f16)acc1;
    if (tbase + 2 < tc) dst[(long)N_DIM * 128] = (f16)acc2;
    if (tbase + 3 < tc) dst[(long)N_DIM * 192] = (f16)acc3;
}

// ---------------- LSTM chunk: named-register weights, 1 barrier/step ----------------
// Wave wv owns gate-types ct={i,f,g,o} x units [16wv,16wv+16). Thread (wv,q,r):
// nodes 4q+reg, unit u=16wv+r -> all 4 gates of (node,u) live in acc{ct}[reg].
// ALL per-thread state is NAMED variables (no arrays) -> register promotion.

#define DECLW(ct, ks) const half8_t w_##ct##_##ks = \
    *(const half8_t*)(wfbuf + (long)((((wv * 4 + ct) * 6 + ks) << 6) + lane) * 8)

#define MFMA(acc, a_, w_) acc = __builtin_amdgcn_mfma_f32_16x16x32_f16(a_, w_, acc, 0, 0, 0)

#define ELEM(reg) { \
    float gi = acc0[reg], gf = acc1[reg], gg = acc2[reg], go = acc3[reg]; \
    float c = sigf(gf) * cv4[reg] + sigf(gi) * tanhfast(gg); \
    float hh = sigf(go) * tanhfast(c); \
    cv4[reg] = c; hv4[reg] = hh; \
    xh[buf ^ 1][4 * q + reg][u] = (f16)hh; }

__global__ __launch_bounds__(512, 1) void k_lstm(
    const f16* __restrict__ ah, const f16* __restrict__ wfbuf,
    const float* __restrict__ gbias,
    const float* __restrict__ Wm1, const float* __restrict__ bm1,
    const float* __restrict__ Wm2, const float* __restrict__ bm2,
    float* __restrict__ Hst, float* __restrict__ Cst,
    int tc, int do_init, int do_head, float* __restrict__ out) {
    __shared__ __align__(16) f16   xh[2][16][136];   // h units, double-buffered
    __shared__ __align__(16) float hd[16][132];
    __shared__ __align__(16) float zs[16][64];

    int tid = threadIdx.x;
    int wv = tid >> 6, lane = tid & 63, q = lane >> 4, r = lane & 15;
    int nb = blockIdx.x * 16;
    int cnt = min(16, N_DIM - nb);
    int u = 16 * wv + r;

    // 24 named weight fragments (96 VGPRs) -- the promotion test
    DECLW(0, 0); DECLW(0, 1); DECLW(0, 2); DECLW(0, 3); DECLW(0, 4); DECLW(0, 5);
    DECLW(1, 0); DECLW(1, 1); DECLW(1, 2); DECLW(1, 3); DECLW(1, 4); DECLW(1, 5);
    DECLW(2, 0); DECLW(2, 1); DECLW(2, 2); DECLW(2, 3); DECLW(2, 4); DECLW(2, 5);
    DECLW(3, 0); DECLW(3, 1); DECLW(3, 2); DECLW(3, 3); DECLW(3, 4); DECLW(3, 5);

    // per-node folded bias: 4 named float4
    int gn0 = nb + 4 * q;     if (gn0 >= N_DIM) gn0 = N_DIM - 1;
    int gn1 = nb + 4 * q + 1; if (gn1 >= N_DIM) gn1 = N_DIM - 1;
    int gn2 = nb + 4 * q + 2; if (gn2 >= N_DIM) gn2 = N_DIM - 1;
    int gn3 = nb + 4 * q + 3; if (gn3 >= N_DIM) gn3 = N_DIM - 1;
    float4_t gb0, gb1, gb2, gb3;
    gb0[0] = gbias[(long)gn0 * 512 + 0 * 128 + u];
    gb0[1] = gbias[(long)gn1 * 512 + 0 * 128 + u];
    gb0[2] = gbias[(long)gn2 * 512 + 0 * 128 + u];
    gb0[3] = gbias[(long)gn3 * 512 + 0 * 128 + u];
    gb1[0] = gbias[(long)gn0 * 512 + 1 * 128 + u];
    gb1[1] = gbias[(long)gn1 * 512 + 1 * 128 + u];
    gb1[2] = gbias[(long)gn2 * 512 + 1 * 128 + u];
    gb1[3] = gbias[(long)gn3 * 512 + 1 * 128 + u];
    gb2[0] = gbias[(long)gn0 * 512 + 2 * 128 + u];
    gb2[1] = gbias[(long)gn1 * 512 + 2 * 128 + u];
    gb2[2] = gbias[(long)gn2 * 512 + 2 * 128 + u];
    gb2[3] = gbias[(long)gn3 * 512 + 2 * 128 + u];
    gb3[0] = gbias[(long)gn0 * 512 + 3 * 128 + u];
    gb3[1] = gbias[(long)gn1 * 512 + 3 * 128 + u];
    gb3[2] = gbias[(long)gn2 * 512 + 3 * 128 + u];
    gb3[3] = gbias[(long)gn3 * 512 + 3 * 128 + u];

    // state: named float4 vectors
    float4_t cv4, hv4;
    {
        int node = 4 * q;
        bool lv0 = (!do_init) && (node < cnt);
        bool lv1 = (!do_init) && (node + 1 < cnt);
        bool lv2 = (!do_init) && (node + 2 < cnt);
        bool lv3 = (!do_init) && (node + 3 < cnt);
        hv4[0] = lv0 ? Hst[(long)(nb + node) * H_DIM + u] : 0.f;
        hv4[1] = lv1 ? Hst[(long)(nb + node + 1) * H_DIM + u] : 0.f;
        hv4[2] = lv2 ? Hst[(long)(nb + node + 2) * H_DIM + u] : 0.f;
        hv4[3] = lv3 ? Hst[(long)(nb + node + 3) * H_DIM + u] : 0.f;
        cv4[0] = lv0 ? Cst[(long)(nb + node) * H_DIM + u] : 0.f;
        cv4[1] = lv1 ? Cst[(long)(nb + node + 1) * H_DIM + u] : 0.f;
        cv4[2] = lv2 ? Cst[(long)(nb + node + 2) * H_DIM + u] : 0.f;
        cv4[3] = lv3 ? Cst[(long)(nb + node + 3) * H_DIM + u] : 0.f;
        xh[0][node][u]     = (f16)hv4[0];
        xh[0][node + 1][u] = (f16)hv4[1];
        xh[0][node + 2][u] = (f16)hv4[2];
        xh[0][node + 3][u] = (f16)hv4[3];
    }

    int xrow = nb + r; if (xrow >= N_DIM) xrow = N_DIM - 1;
    half8_t xa = *(const half8_t*)(ah + (long)xrow * 64 + 8 * q);
    half8_t xb = *(const half8_t*)(ah + (long)xrow * 64 + 32 + 8 * q);

    int buf = 0;
    __syncthreads();

    for (int t = 0; t < tc; t++) {
        half8_t a2 = *(const half8_t*)&xh[buf][r][8 * q];
        half8_t a3 = *(const half8_t*)&xh[buf][r][32 + 8 * q];
        half8_t a4 = *(const half8_t*)&xh[buf][r][64 + 8 * q];
        half8_t a5 = *(const half8_t*)&xh[buf][r][96 + 8 * q];

        float4_t acc0 = gb0, acc1 = gb1, acc2 = gb2, acc3 = gb3;

        MFMA(acc0, xa, w_0_0); MFMA(acc1, xa, w_1_0); MFMA(acc2, xa, w_2_0); MFMA(acc3, xa, w_3_0);
        MFMA(acc0, xb, w_0_1); MFMA(acc1, xb, w_1_1); MFMA(acc2, xb, w_2_1); MFMA(acc3, xb, w_3_1);

        // prefetch next x -- xa/xb dead; latency hides under h-part MFMAs
        int tn = (t + 1 < tc) ? t + 1 : t;
        const f16* xp = ah + ((long)tn * N_DIM + xrow) * 64;
        xa = *(const half8_t*)(xp + 8 * q);
        xb = *(const half8_t*)(xp + 32 + 8 * q);

        MFMA(acc0, a2, w_0_2); MFMA(acc1, a2, w_1_2); MFMA(acc2, a2, w_2_2); MFMA(acc3, a2, w_3_2);
        MFMA(acc0, a3, w_0_3); MFMA(acc1, a3, w_1_3); MFMA(acc2, a3, w_2_3); MFMA(acc3, a3, w_3_3);
        MFMA(acc0, a4, w_0_4); MFMA(acc1, a4, w_1_4); MFMA(acc2, a4, w_2_4); MFMA(acc3, a4, w_3_4);
        MFMA(acc0, a5, w_0_5); MFMA(acc1, a5, w_1_5); MFMA(acc2, a5, w_2_5); MFMA(acc3, a5, w_3_5);

        ELEM(0) ELEM(1) ELEM(2) ELEM(3)

        __syncthreads();
        buf ^= 1;
    }

    {
        int node = 4 * q;
        if (node < cnt)     { Hst[(long)(nb + node) * H_DIM + u] = hv4[0];
                              Cst[(long)(nb + node) * H_DIM + u] = cv4[0]; }
        if (node + 1 < cnt) { Hst[(long)(nb + node + 1) * H_DIM + u] = hv4[1];
                              Cst[(long)(nb + node + 1) * H_DIM + u] = cv4[1]; }
        if (node + 2 < cnt) { Hst[(long)(nb + node + 2) * H_DIM + u] = hv4[2];
                              Cst[(long)(nb + node + 2) * H_DIM + u] = cv4[2]; }
        if (node + 3 < cnt) { Hst[(long)(nb + node + 3) * H_DIM + u] = hv4[3];
                              Cst[(long)(nb + node + 3) * H_DIM + u] = cv4[3]; }
    }
    if (!do_head) return;

    hd[4 * q + 0][u] = hv4[0];
    hd[4 * q + 1][u] = hv4[1];
    hd[4 * q + 2][u] = hv4[2];
    hd[4 * q + 3][u] = hv4[3];
    __syncthreads();

    for (int i = tid; i < 16 * 64; i += 512) {
        int n = i >> 6, m = i & 63;
        float a = bm1[m];
        #pragma unroll 8
        for (int k = 0; k < H_DIM; k++) a += hd[n][k] * Wm1[k * 64 + m];
        zs[n][m] = fmaxf(a, 0.f);
    }
    __syncthreads();
    if (tid < cnt) {
        float a = bm2[0];
        #pragma unroll 8
        for (int m = 0; m < 64; m++) a += zs[tid][m] * Wm2[m];
        out[nb + tid] = a;
    }
}

// ---------------------------------------------------------------------------

extern "C" void kernel_launch(void* const* d_in, const int* in_sizes, int n_in,
                              void* d_out, int out_size, void* d_ws, size_t ws_size,
                              hipStream_t stream) {
    const float* x   = (const float*)d_in[0];
    const int*   ei  = (const int*)d_in[1];
    const float* ew  = (const float*)d_in[2];
    const float* W1  = (const float*)d_in[3];
    const float* b1  = (const float*)d_in[4];
    const float* W2  = (const float*)d_in[5];
    const float* b2  = (const float*)d_in[6];
    const float* cb  = (const float*)d_in[7];
    const float* Wih = (const float*)d_in[8];
    const float* Whh = (const float*)d_in[9];
    const float* bih = (const float*)d_in[10];
    const float* bhh = (const float*)d_in[11];
    const float* Wm1 = (const float*)d_in[12];
    const float* bm1 = (const float*)d_in[13];
    const float* Wm2 = (const float*)d_in[14];
    const float* bm2 = (const float*)d_in[15];
    float* out = (float*)d_out;
    (void)in_sizes; (void)n_in; (void)out_size;

    char* ws = (char*)d_ws;
    size_t off = 0;
    auto alloc = [&](size_t bytes) -> char* {
        char* p = ws + off;
        off = (off + bytes + 255) & ~(size_t)255;
        return p;
    };
    float* dis   = (float*)alloc(N_DIM * 4);
    int*   cnt   = (int*)alloc(N_DIM * 4);
    int*   fill  = (int*)alloc(N_DIM * 4);
    int*   rowp  = (int*)alloc((N_DIM + 1) * 4);
    int*   eid   = (int*)alloc(ET * 4);
    int*   csrc  = (int*)alloc(ET * 4);
    float* cnrm  = (float*)alloc(ET * 4);
    float* Hst   = (float*)alloc((size_t)N_DIM * H_DIM * 4);
    float* Cst   = (float*)alloc((size_t)N_DIM * H_DIM * 4);
    f16*   wfbuf = (f16*)alloc((size_t)8 * 4 * 6 * 64 * 8 * 2);
    float* gbias = (float*)alloc((size_t)N_DIM * 512 * 4);

    // largest Tc dividing 336 whose chunk buffers (rows*320B) fit
    const int cand[] = {336, 168, 112, 84, 56, 48, 28, 16, 8, 4};
    int Tc = 4;
    for (int i = 0; i < 10; i++) {
        size_t need = off + (size_t)cand[i] * N_DIM * 320 + 4096;
        if (need <= ws_size) { Tc = cand[i]; break; }
    }
    long rows = (long)Tc * N_DIM;
    float* aggX  = (float*)alloc(rows * 64);    // [rows][16] fp32 (14 used)
    f16*   hbuf  = (f16*)alloc(rows * 128);     // h f16
    f16*   ahbuf = (f16*)alloc(rows * 128);     // ah f16

    // --- one-time: CSR build + weight fold/pack + per-node gate bias ---
    k_init<<<(N_DIM + 255) / 256, 256, 0, stream>>>(cnt, fill);
    k_cnt<<<(E_DIM + 255) / 256, 256, 0, stream>>>(ei, cnt);
    k_scan<<<1, 1024, 0, stream>>>(cnt, rowp);
    k_fill<<<(ET + 255) / 256, 256, 0, stream>>>(ei, rowp, fill, eid);
    k_sortdeg<<<(N_DIM + 255) / 256, 256, 0, stream>>>(ew, rowp, eid, dis);
    k_csrmat<<<(N_DIM + 255) / 256, 256, 0, stream>>>(ei, ew, dis, rowp, eid, csrc, cnrm);
    k_wprep<<<48, 256, 0, stream>>>(W2, Wih, Whh, wfbuf);
    k_gbias<<<(int)(((long)N_DIM * 512 + 255) / 256), 256, 0, stream>>>(cb, b2, Wih, bih, bhh, gbias);

    int ntg = (Tc + 3) >> 2;
    long aggWaves = (long)N_DIM * ntg;
    int aggBlocks = (int)((aggWaves + 3) / 4);
    int trBlocks  = (int)(((rows + 1) / 2 + 3) / 4);
    int lblocks   = (N_DIM + 15) / 16;
    int nChunks   = T_DIM / Tc;

    for (int c = 0; c < nChunks; c++) {
        long t0 = (long)c * Tc;
        k_aggx<<<aggBlocks, 256, 0, stream>>>(x + t0 * N_DIM * FEAT, rowp, csrc, cnrm, aggX, Tc);
        k_tr1<<<trBlocks, 256, 0, stream>>>(aggX, W1, b1, hbuf, rows);
        k_agg2<<<aggBlocks, 256, 0, stream>>>(hbuf, rowp, csrc, cnrm, ahbuf, Tc);
        k_lstm<<<lblocks, 512, 0, stream>>>(ahbuf, wfbuf, gbias, Wm1, bm1, Wm2, bm2,
                                            Hst, Cst, Tc, c == 0 ? 1 : 0,
                                            c == nChunks - 1 ? 1 : 0, out);
    }
}